// Round 3
// baseline (425.938 us; speedup 1.0000x reference)
//
#include <hip/hip_runtime.h>
#include <hip/hip_bf16.h>

#define N 6144
#define EMB 256
#define HID 128
#define E_POS 98304
#define E_NEG 24576
#define E_POT 262144
#define SIGMA_INV (1.0f / 100.0f)
#define T_DEL 0.1f

#define BATCH 128
#define NB_POS (E_POS / BATCH)            // 768
#define NB_NEG (E_NEG / BATCH)            // 192
#define NB_POT (E_POT / BATCH)            // 2048
#define NB_TOT (NB_POS + NB_NEG + NB_POT) // 3008

__device__ __forceinline__ float sigm(float x) { return 1.0f / (1.0f + __expf(-x)); }

__device__ __forceinline__ unsigned short f2bf(float f) {
    unsigned u = __float_as_uint(f);
    u += 0x7fffu + ((u >> 16) & 1u);
    return (unsigned short)(u >> 16);
}

// unpack 2 bf16 (packed in a uint) to float2
__device__ __forceinline__ float2 bf2f2(unsigned u) {
    return make_float2(__uint_as_float(u << 16), __uint_as_float(u & 0xffff0000u));
}

// accumulate dot of 8 bf16 pairs into float2 (pairwise) — compiler can emit v_pk_fma_f32
__device__ __forceinline__ void dot8acc(uint4 a, uint4 b, float2& s) {
    float2 x, y;
    x = bf2f2(a.x); y = bf2f2(b.x); s.x += x.x * y.x; s.y += x.y * y.y;
    x = bf2f2(a.y); y = bf2f2(b.y); s.x += x.x * y.x; s.y += x.y * y.y;
    x = bf2f2(a.z); y = bf2f2(b.z); s.x += x.x * y.x; s.y += x.y * y.y;
    x = bf2f2(a.w); y = bf2f2(b.w); s.x += x.x * y.x; s.y += x.y * y.y;
}

// ---------------------------------------------------------------------------
// MLP (unchanged structure): latent = relu(emb@W1+b1)@W2+b2, bf16 out.
// Zeroes ws[0..3] (loss accumulators + finalize counter).
// ---------------------------------------------------------------------------
#define ROWS 16
#define EPITCH 260
#define HPITCH 132

__global__ __launch_bounds__(128)
void mlp_kernel(const float* __restrict__ emb,
                const float* __restrict__ Wl1, const float* __restrict__ bl1,
                const float* __restrict__ Wl2, const float* __restrict__ bl2,
                const float* __restrict__ Wa1, const float* __restrict__ ba1,
                const float* __restrict__ Wa2, const float* __restrict__ ba2,
                unsigned short* __restrict__ latL, unsigned short* __restrict__ latA,
                float* __restrict__ ws_acc)
{
    const int t = threadIdx.x;
    const int branch = blockIdx.y;
    const float* W1 = branch ? Wa1 : Wl1;
    const float* b1 = branch ? ba1 : bl1;
    const float* W2 = branch ? Wa2 : Wl2;
    const float* b2 = branch ? ba2 : bl2;
    unsigned short* lat = branch ? latA : latL;

    if (blockIdx.x == 0 && branch == 0 && t < 4) ws_acc[t] = 0.f;

    __shared__ float embS[ROWS * EPITCH];
    __shared__ float hidS[ROWS * HPITCH];

    const int row0 = blockIdx.x * ROWS;

    for (int idx = t; idx < ROWS * (EMB / 4); idx += 128) {
        int r = idx >> 6;
        int c4 = (idx & 63) << 2;
        *(float4*)(embS + r * EPITCH + c4) =
            *(const float4*)(emb + (size_t)(row0 + r) * EMB + c4);
    }
    __syncthreads();

    const int h0 = (t & 63) * 2;
    const int rb = (t >> 6) * 8;

    float accx[8], accy[8];

    {
        float2 bb = *(const float2*)(b1 + h0);
        #pragma unroll
        for (int i = 0; i < 8; i++) { accx[i] = bb.x; accy[i] = bb.y; }
        for (int k = 0; k < EMB; k += 4) {
            float2 w0 = *(const float2*)(W1 + (size_t)(k + 0) * HID + h0);
            float2 w1 = *(const float2*)(W1 + (size_t)(k + 1) * HID + h0);
            float2 w2 = *(const float2*)(W1 + (size_t)(k + 2) * HID + h0);
            float2 w3 = *(const float2*)(W1 + (size_t)(k + 3) * HID + h0);
            #pragma unroll
            for (int i = 0; i < 8; i++) {
                float4 e = *(const float4*)(embS + (rb + i) * EPITCH + k);
                accx[i] += e.x * w0.x + e.y * w1.x + e.z * w2.x + e.w * w3.x;
                accy[i] += e.x * w0.y + e.y * w1.y + e.z * w2.y + e.w * w3.y;
            }
        }
        #pragma unroll
        for (int i = 0; i < 8; i++) {
            *(float2*)(hidS + (rb + i) * HPITCH + h0) =
                make_float2(fmaxf(accx[i], 0.f), fmaxf(accy[i], 0.f));
        }
    }
    __syncthreads();

    {
        float2 bb = *(const float2*)(b2 + h0);
        #pragma unroll
        for (int i = 0; i < 8; i++) { accx[i] = bb.x; accy[i] = bb.y; }
        for (int k = 0; k < HID; k += 4) {
            float2 w0 = *(const float2*)(W2 + (size_t)(k + 0) * HID + h0);
            float2 w1 = *(const float2*)(W2 + (size_t)(k + 1) * HID + h0);
            float2 w2 = *(const float2*)(W2 + (size_t)(k + 2) * HID + h0);
            float2 w3 = *(const float2*)(W2 + (size_t)(k + 3) * HID + h0);
            #pragma unroll
            for (int i = 0; i < 8; i++) {
                float4 e = *(const float4*)(hidS + (rb + i) * HPITCH + k);
                accx[i] += e.x * w0.x + e.y * w1.x + e.z * w2.x + e.w * w3.x;
                accy[i] += e.x * w0.y + e.y * w1.y + e.z * w2.y + e.w * w3.y;
            }
        }
        #pragma unroll
        for (int i = 0; i < 8; i++) {
            *(ushort2*)(lat + (size_t)(row0 + rb + i) * HID + h0) =
                make_ushort2(f2bf(accx[i]), f2bf(accy[i]));
        }
    }
}

// ---------------------------------------------------------------------------
// Edge kernel, batch-phase form. One 128-edge homogeneous batch per block:
//   phase 1: 128 threads gather idx + aa (+fd) in parallel -> LDS
//   phase 2: 8x 16-lane subgroups, 16 edges each, unroll x2 (independent
//            load->dot->shuffle chains), leaders write pw to LDS / local acc
//   phase 3: coalesced out store (poten); block loss reduce + last-block
//            finalize (device-scope atomics + threadfence).
// ---------------------------------------------------------------------------
__global__ __launch_bounds__(128)
void edge_kernel(const unsigned short* __restrict__ latL,
                 const unsigned short* __restrict__ latA,
                 const float* __restrict__ aa, const float* __restrict__ fd,
                 const int* __restrict__ ei, const int* __restrict__ ne,
                 const int* __restrict__ pe,
                 const float* __restrict__ ewp, const float* __restrict__ swp,
                 float* __restrict__ out, float* __restrict__ ws_acc)
{
    const int t = threadIdx.x;
    const int lane = t & 63;
    const int s = t & 15;        // lane in subgroup
    const int sg = t >> 4;       // subgroup 0..7
    const float ew = ewp[0];
    const float sw = swp[0];

    __shared__ int   iS[BATCH], jS[BATCH];
    __shared__ float avS[BATCH], fvS[BATCH];
    __shared__ float pwS[BATCH];

    float lossAcc = 0.f;

    const int b = blockIdx.x;    // grid == NB_TOT, one batch per block
    int cls, base;
    const int* __restrict__ src;
    int half;
    if (b < NB_POS)                { cls = 0; src = ei; base = b * BATCH;            half = E_POS; }
    else if (b < NB_POS + NB_NEG)  { cls = 1; src = ne; base = (b - NB_POS) * BATCH; half = E_NEG; }
    else                           { cls = 2; src = pe; base = (b - NB_POS - NB_NEG) * BATCH; half = E_POT; }

    // ---- phase 1: parallel gathers ----
    {
        const int e = base + t;
        const int i = src[e];
        const int j = src[half + e];
        iS[t] = i; jS[t] = j;
        const size_t o2 = (size_t)i * N + j;
        avS[t] = aa[o2];
        if (cls < 2) fvS[t] = fd[o2];
    }
    __syncthreads();

    // ---- phase 2: dots, unroll x2 ----
    #pragma unroll 2
    for (int le = 0; le < 16; le += 2) {
        const int e0 = sg * 16 + le, e1 = e0 + 1;
        const int i0 = iS[e0], j0 = jS[e0];
        const int i1 = iS[e1], j1 = jS[e1];

        uint4 a0 = ((const uint4*)(latL + (size_t)i0 * HID))[s];
        uint4 b0 = ((const uint4*)(latL + (size_t)j0 * HID))[s];
        uint4 c0 = ((const uint4*)(latA + (size_t)i0 * HID))[s];
        uint4 d0 = ((const uint4*)(latA + (size_t)j0 * HID))[s];
        uint4 a1 = ((const uint4*)(latL + (size_t)i1 * HID))[s];
        uint4 b1 = ((const uint4*)(latL + (size_t)j1 * HID))[s];
        uint4 c1 = ((const uint4*)(latA + (size_t)i1 * HID))[s];
        uint4 d1 = ((const uint4*)(latA + (size_t)j1 * HID))[s];

        float2 sl0 = make_float2(0.f, 0.f), sa0 = make_float2(0.f, 0.f);
        float2 sl1 = make_float2(0.f, 0.f), sa1 = make_float2(0.f, 0.f);
        dot8acc(a0, b0, sl0); dot8acc(c0, d0, sa0);
        dot8acc(a1, b1, sl1); dot8acc(c1, d1, sa1);
        float dl0 = sl0.x + sl0.y, da0 = sa0.x + sa0.y;
        float dl1 = sl1.x + sl1.y, da1 = sa1.x + sa1.y;

        #pragma unroll
        for (int off = 8; off >= 1; off >>= 1) {
            dl0 += __shfl_xor(dl0, off, 64);
            da0 += __shfl_xor(da0, off, 64);
            dl1 += __shfl_xor(dl1, off, 64);
            da1 += __shfl_xor(da1, off, 64);
        }

        if (s == 0) {
            const float p0 = sigm(ew * sigm(dl0) + sw * sigm(da0 * avS[e0]));
            const float p1 = sigm(ew * sigm(dl1) + sw * sigm(da1 * avS[e1]));
            if (cls == 2) {
                pwS[e0] = (p0 < T_DEL) ? 0.f : p0;
                pwS[e1] = (p1 < T_DEL) ? 0.f : p1;
            } else {
                const float f0 = fvS[e0] * SIGMA_INV, f1 = fvS[e1] * SIGMA_INV;
                float w0, w1, d0v, d1v;
                if (cls == 0) { w0 = __expf(-f0 * f0); w1 = __expf(-f1 * f1); d0v = p0 - 1.f; d1v = p1 - 1.f; }
                else          { w0 = __expf(f0 * f0);  w1 = __expf(f1 * f1);  d0v = p0;       d1v = p1; }
                lossAcc += w0 * d0v * d0v + w1 * d1v * d1v;
            }
        }
    }
    __syncthreads();

    // ---- phase 3 ----
    if (cls == 2) {
        out[1 + base + t] = pwS[t];
    }

    // block loss reduce (nonzero only at s==0 lanes; full xor-64 reduce is fine)
    #pragma unroll
    for (int off = 32; off >= 1; off >>= 1)
        lossAcc += __shfl_xor(lossAcc, off, 64);

    __shared__ float redS[2];
    if (lane == 0) redS[t >> 6] = lossAcc;
    __syncthreads();

    if (t == 0) {
        atomicAdd(&ws_acc[0], redS[0] + redS[1]);
        __threadfence();
        int done = atomicAdd((int*)(ws_acc + 2), 1);
        if (done == NB_TOT - 1) {
            float total = atomicAdd(&ws_acc[0], 0.f);  // coherent read
            out[0] = total * ((float)N / (float)(E_POS + E_NEG));
        }
    }
}

extern "C" void kernel_launch(void* const* d_in, const int* in_sizes, int n_in,
                              void* d_out, int out_size, void* d_ws, size_t ws_size,
                              hipStream_t stream)
{
    const float* emb = (const float*)d_in[0];
    const float* aa  = (const float*)d_in[1];
    const float* fd  = (const float*)d_in[2];
    const float* Wl1 = (const float*)d_in[3];
    const float* bl1 = (const float*)d_in[4];
    const float* Wl2 = (const float*)d_in[5];
    const float* bl2 = (const float*)d_in[6];
    const float* Wa1 = (const float*)d_in[7];
    const float* ba1 = (const float*)d_in[8];
    const float* Wa2 = (const float*)d_in[9];
    const float* ba2 = (const float*)d_in[10];
    const float* ewp = (const float*)d_in[11];
    const float* swp = (const float*)d_in[12];
    const int* ei = (const int*)d_in[13];
    const int* ne = (const int*)d_in[14];
    const int* pe = (const int*)d_in[15];

    float* out = (float*)d_out;
    float* ws  = (float*)d_ws;
    // ws: [0..1] loss acc, [2] finalize counter, pad to 256B, then bf16 latents
    unsigned short* latL = (unsigned short*)(ws + 64);
    unsigned short* latA = latL + (size_t)N * HID;

    mlp_kernel<<<dim3(N / ROWS, 2), 128, 0, stream>>>(
        emb, Wl1, bl1, Wl2, bl2, Wa1, ba1, Wa2, ba2, latL, latA, ws);

    edge_kernel<<<NB_TOT, BATCH, 0, stream>>>(
        latL, latA, aa, fd, ei, ne, pe, ewp, swp, out, ws);
}

// Round 4
// 408.977 us; speedup vs baseline: 1.0415x; 1.0415x over previous
//
#include <hip/hip_runtime.h>
#include <hip/hip_bf16.h>

#define N 6144
#define EMB 256
#define HID 128
#define E_POS 98304
#define E_NEG 24576
#define E_POT 262144
#define SIGMA_INV (1.0f / 100.0f)
#define T_DEL 0.1f

#define BATCH 256
#define NB_POS (E_POS / BATCH)            // 384
#define NB_NEG (E_NEG / BATCH)            // 96
#define NB_POT (E_POT / BATCH)            // 1024
#define NB_TOT (NB_POS + NB_NEG + NB_POT) // 1504

typedef __attribute__((ext_vector_type(8))) short bh8;
typedef __attribute__((ext_vector_type(4))) float f32x4;

__device__ __forceinline__ float sigm(float x) { return 1.0f / (1.0f + __expf(-x)); }

__device__ __forceinline__ unsigned short f2bf(float f) {
    unsigned u = __float_as_uint(f);
    u += 0x7fffu + ((u >> 16) & 1u);
    return (unsigned short)(u >> 16);
}

__device__ __forceinline__ bh8 ld8(const unsigned short* p) { return *(const bh8*)p; }

// ---------------------------------------------------------------------------
// MLP (unchanged): latent = relu(emb@W1+b1)@W2+b2, bf16 out.
// Zeroes ws[0..3] (loss accumulator + finalize counter).
// ---------------------------------------------------------------------------
#define ROWS 16
#define EPITCH 260
#define HPITCH 132

__global__ __launch_bounds__(128)
void mlp_kernel(const float* __restrict__ emb,
                const float* __restrict__ Wl1, const float* __restrict__ bl1,
                const float* __restrict__ Wl2, const float* __restrict__ bl2,
                const float* __restrict__ Wa1, const float* __restrict__ ba1,
                const float* __restrict__ Wa2, const float* __restrict__ ba2,
                unsigned short* __restrict__ latL, unsigned short* __restrict__ latA,
                float* __restrict__ ws_acc)
{
    const int t = threadIdx.x;
    const int branch = blockIdx.y;
    const float* W1 = branch ? Wa1 : Wl1;
    const float* b1 = branch ? ba1 : bl1;
    const float* W2 = branch ? Wa2 : Wl2;
    const float* b2 = branch ? ba2 : bl2;
    unsigned short* lat = branch ? latA : latL;

    if (blockIdx.x == 0 && branch == 0 && t < 4) ws_acc[t] = 0.f;

    __shared__ float embS[ROWS * EPITCH];
    __shared__ float hidS[ROWS * HPITCH];

    const int row0 = blockIdx.x * ROWS;

    for (int idx = t; idx < ROWS * (EMB / 4); idx += 128) {
        int r = idx >> 6;
        int c4 = (idx & 63) << 2;
        *(float4*)(embS + r * EPITCH + c4) =
            *(const float4*)(emb + (size_t)(row0 + r) * EMB + c4);
    }
    __syncthreads();

    const int h0 = (t & 63) * 2;
    const int rb = (t >> 6) * 8;

    float accx[8], accy[8];

    {
        float2 bb = *(const float2*)(b1 + h0);
        #pragma unroll
        for (int i = 0; i < 8; i++) { accx[i] = bb.x; accy[i] = bb.y; }
        for (int k = 0; k < EMB; k += 4) {
            float2 w0 = *(const float2*)(W1 + (size_t)(k + 0) * HID + h0);
            float2 w1 = *(const float2*)(W1 + (size_t)(k + 1) * HID + h0);
            float2 w2 = *(const float2*)(W1 + (size_t)(k + 2) * HID + h0);
            float2 w3 = *(const float2*)(W1 + (size_t)(k + 3) * HID + h0);
            #pragma unroll
            for (int i = 0; i < 8; i++) {
                float4 e = *(const float4*)(embS + (rb + i) * EPITCH + k);
                accx[i] += e.x * w0.x + e.y * w1.x + e.z * w2.x + e.w * w3.x;
                accy[i] += e.x * w0.y + e.y * w1.y + e.z * w2.y + e.w * w3.y;
            }
        }
        #pragma unroll
        for (int i = 0; i < 8; i++) {
            *(float2*)(hidS + (rb + i) * HPITCH + h0) =
                make_float2(fmaxf(accx[i], 0.f), fmaxf(accy[i], 0.f));
        }
    }
    __syncthreads();

    {
        float2 bb = *(const float2*)(b2 + h0);
        #pragma unroll
        for (int i = 0; i < 8; i++) { accx[i] = bb.x; accy[i] = bb.y; }
        for (int k = 0; k < HID; k += 4) {
            float2 w0 = *(const float2*)(W2 + (size_t)(k + 0) * HID + h0);
            float2 w1 = *(const float2*)(W2 + (size_t)(k + 1) * HID + h0);
            float2 w2 = *(const float2*)(W2 + (size_t)(k + 2) * HID + h0);
            float2 w3 = *(const float2*)(W2 + (size_t)(k + 3) * HID + h0);
            #pragma unroll
            for (int i = 0; i < 8; i++) {
                float4 e = *(const float4*)(hidS + (rb + i) * HPITCH + k);
                accx[i] += e.x * w0.x + e.y * w1.x + e.z * w2.x + e.w * w3.x;
                accy[i] += e.x * w0.y + e.y * w1.y + e.z * w2.y + e.w * w3.y;
            }
        }
        #pragma unroll
        for (int i = 0; i < 8; i++) {
            *(ushort2*)(lat + (size_t)(row0 + rb + i) * HID + h0) =
                make_ushort2(f2bf(accx[i]), f2bf(accy[i]));
        }
    }
}

// ---------------------------------------------------------------------------
// Edge kernel, MFMA form. Block = 256 threads = 4 waves, one 256-edge
// homogeneous batch. Phase 1: all 256 threads gather idx/aa(/fd) -> LDS.
// Phase 2: each wave does 4 iterations of 16 edges via mfma_f32_16x16x32_bf16:
//   A[m][k] = latL[i_m][k]  (lane m=lane&15 loads 8 bf16 at k=quad*8+32*step)
//   B[k][n] = latL[j_n][k]  (same fetch shape)
//   diag D[m][m] = the edge dot; lands at lane {quad==m>>2}, reg=m&3.
// No cross-lane reduce, no VALU dots. Phase 3: coalesced pw store + block
// loss reduce + last-block finalize.
// ---------------------------------------------------------------------------
__global__ __launch_bounds__(256)
void edge_kernel(const unsigned short* __restrict__ latL,
                 const unsigned short* __restrict__ latA,
                 const float* __restrict__ aa, const float* __restrict__ fd,
                 const int* __restrict__ ei, const int* __restrict__ ne,
                 const int* __restrict__ pe,
                 const float* __restrict__ ewp, const float* __restrict__ swp,
                 float* __restrict__ out, float* __restrict__ ws_acc)
{
    const int t = threadIdx.x;
    const int lane = t & 63;
    const int wslot = t >> 6;       // wave 0..3
    const int m = lane & 15;        // edge-in-group / matrix row+col
    const int quad = lane >> 4;
    const float ew = ewp[0];
    const float sw = swp[0];

    __shared__ int   iS[BATCH], jS[BATCH];
    __shared__ float avS[BATCH], fvS[BATCH];
    __shared__ float pwS[BATCH];

    float lossAcc = 0.f;

    const int b = blockIdx.x;
    int cls, base;
    const int* __restrict__ src;
    int half;
    if (b < NB_POS)                { cls = 0; src = ei; base = b * BATCH;            half = E_POS; }
    else if (b < NB_POS + NB_NEG)  { cls = 1; src = ne; base = (b - NB_POS) * BATCH; half = E_NEG; }
    else                           { cls = 2; src = pe; base = (b - NB_POS - NB_NEG) * BATCH; half = E_POT; }

    // ---- phase 1: parallel gathers ----
    {
        const int e = base + t;
        const int i = src[e];
        const int j = src[half + e];
        iS[t] = i; jS[t] = j;
        const size_t o2 = (size_t)i * N + j;
        avS[t] = aa[o2];
        if (cls < 2) fvS[t] = fd[o2];
    }
    __syncthreads();

    // ---- phase 2: MFMA dots, 16 edges per wave-iteration ----
    const int koff = quad * 8;   // element offset of this lane's 8 bf16
    const bool diag = (quad == (m >> 2));
    const int r = lane & 3;      // acc register holding D[m][m] on diag lanes

    #pragma unroll 1
    for (int it = 0; it < 4; ++it) {
        const int e0 = (wslot << 6) + (it << 4);
        const int i = iS[e0 + m];
        const int j = jS[e0 + m];
        const unsigned short* Li = latL + (size_t)i * HID + koff;
        const unsigned short* Lj = latL + (size_t)j * HID + koff;
        const unsigned short* Ai = latA + (size_t)i * HID + koff;
        const unsigned short* Aj = latA + (size_t)j * HID + koff;

        bh8 aL0 = ld8(Li), aL1 = ld8(Li + 32), aL2 = ld8(Li + 64), aL3 = ld8(Li + 96);
        bh8 bL0 = ld8(Lj), bL1 = ld8(Lj + 32), bL2 = ld8(Lj + 64), bL3 = ld8(Lj + 96);
        bh8 aA0 = ld8(Ai), aA1 = ld8(Ai + 32), aA2 = ld8(Ai + 64), aA3 = ld8(Ai + 96);
        bh8 bA0 = ld8(Aj), bA1 = ld8(Aj + 32), bA2 = ld8(Aj + 64), bA3 = ld8(Aj + 96);

        f32x4 accL = {0.f, 0.f, 0.f, 0.f};
        f32x4 accA = {0.f, 0.f, 0.f, 0.f};
        accL = __builtin_amdgcn_mfma_f32_16x16x32_bf16(aL0, bL0, accL, 0, 0, 0);
        accA = __builtin_amdgcn_mfma_f32_16x16x32_bf16(aA0, bA0, accA, 0, 0, 0);
        accL = __builtin_amdgcn_mfma_f32_16x16x32_bf16(aL1, bL1, accL, 0, 0, 0);
        accA = __builtin_amdgcn_mfma_f32_16x16x32_bf16(aA1, bA1, accA, 0, 0, 0);
        accL = __builtin_amdgcn_mfma_f32_16x16x32_bf16(aL2, bL2, accL, 0, 0, 0);
        accA = __builtin_amdgcn_mfma_f32_16x16x32_bf16(aA2, bA2, accA, 0, 0, 0);
        accL = __builtin_amdgcn_mfma_f32_16x16x32_bf16(aL3, bL3, accL, 0, 0, 0);
        accA = __builtin_amdgcn_mfma_f32_16x16x32_bf16(aA3, bA3, accA, 0, 0, 0);

        // diagonal extraction: reg index r = lane&3 (divergent -> cndmask chain)
        float dl = r == 3 ? accL[3] : (r == 2 ? accL[2] : (r == 1 ? accL[1] : accL[0]));
        float da = r == 3 ? accA[3] : (r == 2 ? accA[2] : (r == 1 ? accA[1] : accA[0]));

        if (diag) {
            const int e = e0 + m;
            const float p = sigm(ew * sigm(dl) + sw * sigm(da * avS[e]));
            if (cls == 2) {
                pwS[e] = (p < T_DEL) ? 0.f : p;
            } else {
                const float f = fvS[e] * SIGMA_INV;
                const float f2 = f * f;
                const float w = (cls == 0) ? __expf(-f2) : __expf(f2);
                const float d = (cls == 0) ? p - 1.f : p;
                lossAcc += w * d * d;
            }
        }
    }
    __syncthreads();

    // ---- phase 3 ----
    if (cls == 2) {
        out[1 + base + t] = pwS[t];
    }

    #pragma unroll
    for (int off = 32; off >= 1; off >>= 1)
        lossAcc += __shfl_xor(lossAcc, off, 64);

    __shared__ float redS[4];
    if (lane == 0) redS[wslot] = lossAcc;
    __syncthreads();

    if (t == 0) {
        atomicAdd(&ws_acc[0], redS[0] + redS[1] + redS[2] + redS[3]);
        __threadfence();
        int done = atomicAdd((int*)(ws_acc + 2), 1);
        if (done == NB_TOT - 1) {
            float total = atomicAdd(&ws_acc[0], 0.f);  // coherent read
            out[0] = total * ((float)N / (float)(E_POS + E_NEG));
        }
    }
}

extern "C" void kernel_launch(void* const* d_in, const int* in_sizes, int n_in,
                              void* d_out, int out_size, void* d_ws, size_t ws_size,
                              hipStream_t stream)
{
    const float* emb = (const float*)d_in[0];
    const float* aa  = (const float*)d_in[1];
    const float* fd  = (const float*)d_in[2];
    const float* Wl1 = (const float*)d_in[3];
    const float* bl1 = (const float*)d_in[4];
    const float* Wl2 = (const float*)d_in[5];
    const float* bl2 = (const float*)d_in[6];
    const float* Wa1 = (const float*)d_in[7];
    const float* ba1 = (const float*)d_in[8];
    const float* Wa2 = (const float*)d_in[9];
    const float* ba2 = (const float*)d_in[10];
    const float* ewp = (const float*)d_in[11];
    const float* swp = (const float*)d_in[12];
    const int* ei = (const int*)d_in[13];
    const int* ne = (const int*)d_in[14];
    const int* pe = (const int*)d_in[15];

    float* out = (float*)d_out;
    float* ws  = (float*)d_ws;
    // ws: [0..1] loss acc, [2] finalize counter, pad to 256B, then bf16 latents
    unsigned short* latL = (unsigned short*)(ws + 64);
    unsigned short* latA = latL + (size_t)N * HID;

    mlp_kernel<<<dim3(N / ROWS, 2), 128, 0, stream>>>(
        emb, Wl1, bl1, Wl2, bl2, Wa1, ba1, Wa2, ba2, latL, latA, ws);

    edge_kernel<<<NB_TOT, BATCH, 0, stream>>>(
        latL, latA, aa, fd, ei, ne, pe, ewp, swp, out, ws);
}